// Round 6
// baseline (806.830 us; speedup 1.0000x reference)
//
#include <hip/hip_runtime.h>
#include <hip/hip_bf16.h>

#define N_NODES 50000
#define N_EDGES 1600000
#define IN_DIM 1024
#define HID 128

typedef __bf16 bf16x8 __attribute__((ext_vector_type(8)));
typedef float f32x4 __attribute__((ext_vector_type(4)));
typedef __bf16 bf16x4 __attribute__((ext_vector_type(4)));

// bf16-pair (packed in uint) -> 2 floats
__device__ __forceinline__ float2 bf2f(unsigned u) {
    return make_float2(__uint_as_float(u << 16), __uint_as_float(u & 0xffff0000u));
}
__device__ __forceinline__ float lrelu(float v) { return v > 0.f ? v : 0.2f * v; }

// ---------------------------------------------------------------- init
__global__ void init_kernel(int* __restrict__ deg, float* __restrict__ out, int out_n) {
    int i = blockIdx.x * 256 + threadIdx.x;
    if (i < N_NODES) deg[i] = 0;
    if (i < out_n) out[i] = 0.0f;
}

// ---------------------------------------------------------------- W^T -> bf16  (wt[n][k], 128x1024)
__global__ void wtrans_kernel(const float* __restrict__ W, __bf16* __restrict__ wt) {
    int i = blockIdx.x * 256 + threadIdx.x;
    int n = i >> 10, k = i & 1023;
    wt[i] = (__bf16)W[(size_t)k * HID + n];
}

// ---------------------------------------------------------------- GEMM h = x @ W (bf16 MFMA)
// + fused att epilogue: a_src/a_dst from fp32 acc fragments (16-lane shfl reduce).
__global__ __launch_bounds__(256) void gemm_kernel(const float* __restrict__ x,
                                                   const __bf16* __restrict__ wt,
                                                   __bf16* __restrict__ h2,
                                                   const float* __restrict__ att_s,
                                                   const float* __restrict__ att_d,
                                                   float* __restrict__ o_as,
                                                   float* __restrict__ o_ad) {
    __shared__ __bf16 xa[128][40];
    __shared__ __bf16 wb[128][40];
    const int t = threadIdx.x;
    const int m0 = blockIdx.x * 128;
    const int wid = t >> 6, lane = t & 63;
    const int lm = lane & 15, q8 = (lane >> 4) * 8;
    const int rw0 = wid * 32;

    f32x4 acc[2][8] = {};
    for (int k0 = 0; k0 < IN_DIM; k0 += 32) {
#pragma unroll
        for (int l = 0; l < 4; ++l) {
            int f = t + l * 256;
            int row = f >> 3, kq = f & 7;
            int gr = m0 + row;
            float4 v = make_float4(0.f, 0.f, 0.f, 0.f);
            if (gr < N_NODES)
                v = *(const float4*)(x + (size_t)gr * IN_DIM + k0 + kq * 4);
            bf16x4 b; b[0] = (__bf16)v.x; b[1] = (__bf16)v.y; b[2] = (__bf16)v.z; b[3] = (__bf16)v.w;
            *(bf16x4*)&xa[row][kq * 4] = b;
        }
#pragma unroll
        for (int l = 0; l < 4; ++l) {
            int f = t + l * 256;
            int n = f >> 3, c = f & 7;
            *(uint2*)&wb[n][c * 4] = *(const uint2*)(wt + (size_t)n * IN_DIM + k0 + c * 4);
        }
        __syncthreads();
        bf16x8 af0 = *(const bf16x8*)&xa[rw0 + lm][q8];
        bf16x8 af1 = *(const bf16x8*)&xa[rw0 + 16 + lm][q8];
#pragma unroll
        for (int ct = 0; ct < 8; ++ct) {
            bf16x8 bfr = *(const bf16x8*)&wb[ct * 16 + lm][q8];
            acc[0][ct] = __builtin_amdgcn_mfma_f32_16x16x32_bf16(af0, bfr, acc[0][ct], 0, 0, 0);
            acc[1][ct] = __builtin_amdgcn_mfma_f32_16x16x32_bf16(af1, bfr, acc[1][ct], 0, 0, 0);
        }
        __syncthreads();
    }
    const int quad = lane >> 4;
    float attsf[8], attdf[8];
#pragma unroll
    for (int ct = 0; ct < 8; ++ct) {
        attsf[ct] = att_s[ct * 16 + lm];
        attdf[ct] = att_d[ct * 16 + lm];
    }
#pragma unroll
    for (int rt = 0; rt < 2; ++rt) {
#pragma unroll
        for (int reg = 0; reg < 4; ++reg) {
            int row = m0 + rw0 + rt * 16 + quad * 4 + reg;
            float ps = 0.f, pd = 0.f;
#pragma unroll
            for (int ct = 0; ct < 8; ++ct) {
                float v = acc[rt][ct][reg];
                ps = fmaf(v, attsf[ct], ps);
                pd = fmaf(v, attdf[ct], pd);
            }
#pragma unroll
            for (int o = 8; o; o >>= 1) {
                ps += __shfl_xor(ps, o);
                pd += __shfl_xor(pd, o);
            }
            if (row < N_NODES) {
                if (lm == 0) { o_as[row] = ps; o_ad[row] = pd; }
#pragma unroll
                for (int ct = 0; ct < 8; ++ct)
                    h2[(size_t)row * HID + ct * 16 + lm] = (__bf16)acc[rt][ct][reg];
            }
        }
    }
}

// ---------------------------------------------------------------- CSR build
__global__ void hist_kernel(const int* __restrict__ ei, int* __restrict__ deg) {
    int e = blockIdx.x * 256 + threadIdx.x;
    if (e < N_EDGES) atomicAdd(&deg[ei[N_EDGES + e]], 1);
}

__global__ void scan1_kernel(const int* __restrict__ deg, int* __restrict__ bsum) {
    int b = blockIdx.x, t = threadIdx.x;
    int base = b * 1024 + t * 4;
    int s = 0;
#pragma unroll
    for (int j = 0; j < 4; ++j) {
        int idx = base + j;
        if (idx < N_NODES) s += deg[idx];
    }
    for (int o = 32; o; o >>= 1) s += __shfl_xor(s, o);
    __shared__ int wsum[4];
    int lane = t & 63, w = t >> 6;
    if (lane == 0) wsum[w] = s;
    __syncthreads();
    if (t == 0) bsum[b] = wsum[0] + wsum[1] + wsum[2] + wsum[3];
}

__global__ void scan2_kernel(const int* __restrict__ bsum, int* __restrict__ boff,
                             int* __restrict__ rowstart, int nb) {
    if (threadIdx.x == 0 && blockIdx.x == 0) {
        int run = 0;
        for (int i = 0; i < nb; ++i) { boff[i] = run; run += bsum[i]; }
        rowstart[N_NODES] = run;
    }
}

__global__ void scan3_kernel(int* __restrict__ deg, const int* __restrict__ boff,
                             int* __restrict__ rowstart) {
    int b = blockIdx.x, t = threadIdx.x;
    int base = b * 1024 + t * 4;
    int v[4]; int s = 0;
#pragma unroll
    for (int j = 0; j < 4; ++j) {
        int idx = base + j;
        v[j] = (idx < N_NODES) ? deg[idx] : 0;
        s += v[j];
    }
    int lane = t & 63, w = t >> 6;
    int inc = s;
    for (int o = 1; o < 64; o <<= 1) {
        int u = __shfl_up(inc, o);
        if (lane >= o) inc += u;
    }
    __shared__ int wt[4];
    if (lane == 63) wt[w] = inc;
    __syncthreads();
    int woff = 0;
    for (int i = 0; i < w; ++i) woff += wt[i];
    int run = woff + inc - s + boff[b];
#pragma unroll
    for (int j = 0; j < 4; ++j) {
        int idx = base + j;
        if (idx < N_NODES) {
            rowstart[idx] = run;
            run += v[j];
            deg[idx] = 0;   // re-zero: reused as scatter cursor
        }
    }
}

// scatter: CSR slot gets (src, a_src[src]); a_dst folded in at aggregate (wave-uniform).
__global__ void scatter_kernel(const int* __restrict__ ei, const int* __restrict__ rowstart,
                               int* __restrict__ cursor, uint2* __restrict__ csrp,
                               const float* __restrict__ a_src) {
    int e = blockIdx.x * 256 + threadIdx.x;
    if (e >= N_EDGES) return;
    int s = ei[e], d = ei[N_EDGES + e];
    int pos = atomicAdd(&cursor[d], 1);
    uint2 v; v.x = (unsigned)s; v.y = __float_as_uint(a_src[s]);
    csrp[rowstart[d] + pos] = v;
}

// ---------------------------------------------------------------- aggregate+pool
// One wave per dst node. Half-wave edge pairing: lane = sub*32 + l5; lane covers
// features 4*l5..4*l5+3 (uint2 = 4 bf16); sub=0 handles even edges, sub=1 odd.
// ALL __shfl broadcasts are executed with the full wave active (no shfl inside
// divergent code: ds_bpermute only sees data pushed by ACTIVE lanes).
__global__ __launch_bounds__(256) void aggregate_kernel(
    const uint2* __restrict__ h2u2, const float* __restrict__ a_src,
    const float* __restrict__ a_dst, const int* __restrict__ rowstart,
    const uint2* __restrict__ csrp, const float* __restrict__ bias,
    const int* __restrict__ batch, float* __restrict__ out) {
    int wid = threadIdx.x >> 6, lane = threadIdx.x & 63;
    int n = blockIdx.x * 4 + wid;
    if (n >= N_NODES) return;
    const int sub = lane >> 5, l5 = lane & 31;
    int rs = rowstart[n], re = rowstart[n + 1];
    float adn = a_dst[n];
    float pself = __expf(lrelu(a_src[n] + adn));
    float denom = pself;
    f32x4 acc = {0.f, 0.f, 0.f, 0.f};
    {   // self-loop counted once (acc is duplicated per half); no divergence
        uint2 us = h2u2[(size_t)n * 32 + l5];
        float2 g0 = bf2f(us.x), g1 = bf2f(us.y);
        float w = (sub == 0) ? pself : 0.f;
        acc[0] = w * g0.x; acc[1] = w * g0.y;
        acc[2] = w * g1.x; acc[3] = w * g1.y;
    }
    for (int base = rs; base < re; base += 64) {
        int cnt = re - base; if (cnt > 64) cnt = 64;
        uint2 sp = make_uint2(0u, 0u);
        bool valid = (base + lane < re);
        if (valid) sp = csrp[base + lane];
        float pe = valid ? __expf(lrelu(__uint_as_float(sp.y) + adn)) : 0.f;
        float ds = pe;
        for (int o = 32; o; o >>= 1) ds += __shfl_xor(ds, o);
        denom += ds;
        int e = 0;
        for (; e + 32 <= cnt; e += 32) {
            uint2 uu[16]; float pp[16];
#pragma unroll
            for (int i = 0; i < 16; ++i) {
                int idx = e + 2 * i + sub;
                unsigned src = (unsigned)__shfl((int)sp.x, idx);
                pp[i] = __shfl(pe, idx);
                uu[i] = h2u2[(size_t)src * 32 + l5];
            }
#pragma unroll
            for (int i = 0; i < 16; ++i) {
                float2 g0 = bf2f(uu[i].x), g1 = bf2f(uu[i].y);
                acc[0] = fmaf(pp[i], g0.x, acc[0]);
                acc[1] = fmaf(pp[i], g0.y, acc[1]);
                acc[2] = fmaf(pp[i], g1.x, acc[2]);
                acc[3] = fmaf(pp[i], g1.y, acc[3]);
            }
        }
        for (; e + 2 <= cnt; e += 2) {
            int idx = e + sub;
            unsigned src = (unsigned)__shfl((int)sp.x, idx);
            float p = __shfl(pe, idx);
            uint2 u = h2u2[(size_t)src * 32 + l5];
            float2 g0 = bf2f(u.x), g1 = bf2f(u.y);
            acc[0] = fmaf(p, g0.x, acc[0]);
            acc[1] = fmaf(p, g0.y, acc[1]);
            acc[2] = fmaf(p, g1.x, acc[2]);
            acc[3] = fmaf(p, g1.y, acc[3]);
        }
        if (e < cnt) {                    // single leftover edge: broadcast with FULL wave,
            unsigned src = (unsigned)__shfl((int)sp.x, e);   // then mask to sub=0 half
            float pbc = __shfl(pe, e);
            float p = (sub == 0) ? pbc : 0.f;
            uint2 u = h2u2[(size_t)src * 32 + l5];
            float2 g0 = bf2f(u.x), g1 = bf2f(u.y);
            acc[0] = fmaf(p, g0.x, acc[0]);
            acc[1] = fmaf(p, g0.y, acc[1]);
            acc[2] = fmaf(p, g1.x, acc[2]);
            acc[3] = fmaf(p, g1.y, acc[3]);
        }
    }
#pragma unroll
    for (int c = 0; c < 4; ++c) acc[c] += __shfl_xor(acc[c], 32);
    if (sub == 0) {
        float inv = 1.0f / denom;
        float4 bv = *(const float4*)(bias + 4 * l5);
        float o0 = fmaxf(acc[0] * inv + bv.x, 0.0f);
        float o1 = fmaxf(acc[1] * inv + bv.y, 0.0f);
        float o2 = fmaxf(acc[2] * inv + bv.z, 0.0f);
        float o3 = fmaxf(acc[3] * inv + bv.w, 0.0f);
        int g = batch[n];
        unsigned* outp = (unsigned*)(out + (size_t)g * HID + 4 * l5);
        atomicMax(&outp[0], __float_as_uint(o0));
        atomicMax(&outp[1], __float_as_uint(o1));
        atomicMax(&outp[2], __float_as_uint(o2));
        atomicMax(&outp[3], __float_as_uint(o3));
    }
}

// ---------------------------------------------------------------- launch
extern "C" void kernel_launch(void* const* d_in, const int* in_sizes, int n_in,
                              void* d_out, int out_size, void* d_ws, size_t ws_size,
                              hipStream_t stream) {
    const float* x     = (const float*)d_in[0];
    const float* W     = (const float*)d_in[1];
    const float* att_s = (const float*)d_in[2];
    const float* att_d = (const float*)d_in[3];
    const float* bias  = (const float*)d_in[4];
    const int*   ei    = (const int*)d_in[5];
    const int*   batch = (const int*)d_in[6];
    float*       out   = (float*)d_out;

    char* ws = (char*)d_ws;
    size_t off = 0;
    auto alloc = [&](size_t bytes) -> void* {
        void* p = ws + off;
        off += (bytes + 255) & ~(size_t)255;
        return p;
    };
    const int NB = (N_NODES + 1023) / 1024;   // 49
    __bf16* h2       = (__bf16*)alloc((size_t)N_NODES * HID * 2);
    __bf16* wt       = (__bf16*)alloc((size_t)HID * IN_DIM * 2);
    float*  a_src    = (float*)alloc((size_t)N_NODES * 4);
    float*  a_dst    = (float*)alloc((size_t)N_NODES * 4);
    int*    deg      = (int*)alloc((size_t)N_NODES * 4);
    int*    rowstart = (int*)alloc((size_t)(N_NODES + 1) * 4);
    int*    bsum     = (int*)alloc((size_t)NB * 4);
    int*    boff     = (int*)alloc((size_t)NB * 4);
    uint2*  csrp     = (uint2*)alloc((size_t)N_EDGES * 8);
    (void)ws_size; (void)in_sizes; (void)n_in;

    int init_n = (N_NODES > out_size ? N_NODES : out_size);
    hipLaunchKernelGGL(init_kernel, dim3((init_n + 255) / 256), dim3(256), 0, stream,
                       deg, out, out_size);
    hipLaunchKernelGGL(wtrans_kernel, dim3((HID * IN_DIM) / 256), dim3(256), 0, stream,
                       W, wt);
    hipLaunchKernelGGL(gemm_kernel, dim3((N_NODES + 127) / 128), dim3(256), 0, stream,
                       x, wt, h2, att_s, att_d, a_src, a_dst);
    hipLaunchKernelGGL(hist_kernel, dim3((N_EDGES + 255) / 256), dim3(256), 0, stream,
                       ei, deg);
    hipLaunchKernelGGL(scan1_kernel, dim3(NB), dim3(256), 0, stream, deg, bsum);
    hipLaunchKernelGGL(scan2_kernel, dim3(1), dim3(64), 0, stream, bsum, boff, rowstart, NB);
    hipLaunchKernelGGL(scan3_kernel, dim3(NB), dim3(256), 0, stream, deg, boff, rowstart);
    hipLaunchKernelGGL(scatter_kernel, dim3((N_EDGES + 255) / 256), dim3(256), 0, stream,
                       ei, rowstart, deg, csrp, a_src);
    hipLaunchKernelGGL(aggregate_kernel, dim3((N_NODES + 3) / 4), dim3(256), 0, stream,
                       (const uint2*)h2, a_src, a_dst, rowstart, csrp, bias, batch, out);
}

// Round 7
// 713.513 us; speedup vs baseline: 1.1308x; 1.1308x over previous
//
#include <hip/hip_runtime.h>
#include <hip/hip_bf16.h>

#define N_NODES 50000
#define N_EDGES 1600000
#define IN_DIM 1024
#define HID 128
#define AGG_WAVES 8192          // 2048 blocks x 4 waves

typedef __bf16 bf16x8 __attribute__((ext_vector_type(8)));
typedef float f32x4 __attribute__((ext_vector_type(4)));
typedef __bf16 bf16x4 __attribute__((ext_vector_type(4)));

// bf16-pair (packed in uint) -> 2 floats (features 2l = low, 2l+1 = high)
__device__ __forceinline__ float2 bf2f(unsigned u) {
    return make_float2(__uint_as_float(u << 16), __uint_as_float(u & 0xffff0000u));
}
__device__ __forceinline__ float lrelu(float v) { return v > 0.f ? v : 0.2f * v; }

// ---------------------------------------------------------------- init
__global__ void init_kernel(int* __restrict__ deg, float* __restrict__ out, int out_n) {
    int i = blockIdx.x * 256 + threadIdx.x;
    if (i < N_NODES) deg[i] = 0;
    if (i < out_n) out[i] = 0.0f;
}

// ---------------------------------------------------------------- W^T -> bf16  (wt[n][k], 128x1024)
__global__ void wtrans_kernel(const float* __restrict__ W, __bf16* __restrict__ wt) {
    int i = blockIdx.x * 256 + threadIdx.x;
    int n = i >> 10, k = i & 1023;
    wt[i] = (__bf16)W[(size_t)k * HID + n];
}

// ---------------------------------------------------------------- GEMM h = x @ W (bf16 MFMA)
// + fused att epilogue: a_src/a_dst from fp32 acc fragments (16-lane shfl reduce).
__global__ __launch_bounds__(256) void gemm_kernel(const float* __restrict__ x,
                                                   const __bf16* __restrict__ wt,
                                                   __bf16* __restrict__ h2,
                                                   const float* __restrict__ att_s,
                                                   const float* __restrict__ att_d,
                                                   float* __restrict__ o_as,
                                                   float* __restrict__ o_ad) {
    __shared__ __bf16 xa[128][40];
    __shared__ __bf16 wb[128][40];
    const int t = threadIdx.x;
    const int m0 = blockIdx.x * 128;
    const int wid = t >> 6, lane = t & 63;
    const int lm = lane & 15, q8 = (lane >> 4) * 8;
    const int rw0 = wid * 32;

    f32x4 acc[2][8] = {};
    for (int k0 = 0; k0 < IN_DIM; k0 += 32) {
#pragma unroll
        for (int l = 0; l < 4; ++l) {
            int f = t + l * 256;
            int row = f >> 3, kq = f & 7;
            int gr = m0 + row;
            float4 v = make_float4(0.f, 0.f, 0.f, 0.f);
            if (gr < N_NODES)
                v = *(const float4*)(x + (size_t)gr * IN_DIM + k0 + kq * 4);
            bf16x4 b; b[0] = (__bf16)v.x; b[1] = (__bf16)v.y; b[2] = (__bf16)v.z; b[3] = (__bf16)v.w;
            *(bf16x4*)&xa[row][kq * 4] = b;
        }
#pragma unroll
        for (int l = 0; l < 4; ++l) {
            int f = t + l * 256;
            int n = f >> 3, c = f & 7;
            *(uint2*)&wb[n][c * 4] = *(const uint2*)(wt + (size_t)n * IN_DIM + k0 + c * 4);
        }
        __syncthreads();
        bf16x8 af0 = *(const bf16x8*)&xa[rw0 + lm][q8];
        bf16x8 af1 = *(const bf16x8*)&xa[rw0 + 16 + lm][q8];
#pragma unroll
        for (int ct = 0; ct < 8; ++ct) {
            bf16x8 bfr = *(const bf16x8*)&wb[ct * 16 + lm][q8];
            acc[0][ct] = __builtin_amdgcn_mfma_f32_16x16x32_bf16(af0, bfr, acc[0][ct], 0, 0, 0);
            acc[1][ct] = __builtin_amdgcn_mfma_f32_16x16x32_bf16(af1, bfr, acc[1][ct], 0, 0, 0);
        }
        __syncthreads();
    }
    const int quad = lane >> 4;
    float attsf[8], attdf[8];
#pragma unroll
    for (int ct = 0; ct < 8; ++ct) {
        attsf[ct] = att_s[ct * 16 + lm];
        attdf[ct] = att_d[ct * 16 + lm];
    }
#pragma unroll
    for (int rt = 0; rt < 2; ++rt) {
#pragma unroll
        for (int reg = 0; reg < 4; ++reg) {
            int row = m0 + rw0 + rt * 16 + quad * 4 + reg;
            float ps = 0.f, pd = 0.f;
#pragma unroll
            for (int ct = 0; ct < 8; ++ct) {
                float v = acc[rt][ct][reg];
                ps = fmaf(v, attsf[ct], ps);
                pd = fmaf(v, attdf[ct], pd);
            }
#pragma unroll
            for (int o = 8; o; o >>= 1) {
                ps += __shfl_xor(ps, o);
                pd += __shfl_xor(pd, o);
            }
            if (row < N_NODES) {
                if (lm == 0) { o_as[row] = ps; o_ad[row] = pd; }
#pragma unroll
                for (int ct = 0; ct < 8; ++ct)
                    h2[(size_t)row * HID + ct * 16 + lm] = (__bf16)acc[rt][ct][reg];
            }
        }
    }
}

// ---------------------------------------------------------------- CSR build
__global__ void hist_kernel(const int* __restrict__ ei, int* __restrict__ deg) {
    int e = blockIdx.x * 256 + threadIdx.x;
    if (e < N_EDGES) atomicAdd(&deg[ei[N_EDGES + e]], 1);
}

__global__ void scan1_kernel(const int* __restrict__ deg, int* __restrict__ bsum) {
    int b = blockIdx.x, t = threadIdx.x;
    int base = b * 1024 + t * 4;
    int s = 0;
#pragma unroll
    for (int j = 0; j < 4; ++j) {
        int idx = base + j;
        if (idx < N_NODES) s += deg[idx];
    }
    for (int o = 32; o; o >>= 1) s += __shfl_xor(s, o);
    __shared__ int wsum[4];
    int lane = t & 63, w = t >> 6;
    if (lane == 0) wsum[w] = s;
    __syncthreads();
    if (t == 0) bsum[b] = wsum[0] + wsum[1] + wsum[2] + wsum[3];
}

__global__ void scan2_kernel(const int* __restrict__ bsum, int* __restrict__ boff,
                             int* __restrict__ rowstart, int nb) {
    if (threadIdx.x == 0 && blockIdx.x == 0) {
        int run = 0;
        for (int i = 0; i < nb; ++i) { boff[i] = run; run += bsum[i]; }
        rowstart[N_NODES] = run;
    }
}

__global__ void scan3_kernel(int* __restrict__ deg, const int* __restrict__ boff,
                             int* __restrict__ rowstart) {
    int b = blockIdx.x, t = threadIdx.x;
    int base = b * 1024 + t * 4;
    int v[4]; int s = 0;
#pragma unroll
    for (int j = 0; j < 4; ++j) {
        int idx = base + j;
        v[j] = (idx < N_NODES) ? deg[idx] : 0;
        s += v[j];
    }
    int lane = t & 63, w = t >> 6;
    int inc = s;
    for (int o = 1; o < 64; o <<= 1) {
        int u = __shfl_up(inc, o);
        if (lane >= o) inc += u;
    }
    __shared__ int wt[4];
    if (lane == 63) wt[w] = inc;
    __syncthreads();
    int woff = 0;
    for (int i = 0; i < w; ++i) woff += wt[i];
    int run = woff + inc - s + boff[b];
#pragma unroll
    for (int j = 0; j < 4; ++j) {
        int idx = base + j;
        if (idx < N_NODES) {
            rowstart[idx] = run;
            run += v[j];
            deg[idx] = 0;   // re-zero: reused as scatter cursor
        }
    }
}

// scatter: CSR slot gets (src, a_src[src]); a_dst folded in at aggregate (wave-uniform).
__global__ void scatter_kernel(const int* __restrict__ ei, const int* __restrict__ rowstart,
                               int* __restrict__ cursor, uint2* __restrict__ csrp,
                               const float* __restrict__ a_src) {
    int e = blockIdx.x * 256 + threadIdx.x;
    if (e >= N_EDGES) return;
    int s = ei[e], d = ei[N_EDGES + e];
    int pos = atomicAdd(&cursor[d], 1);
    uint2 v; v.x = (unsigned)s; v.y = __float_as_uint(a_src[s]);
    csrp[rowstart[d] + pos] = v;
}

// ---------------------------------------------------------------- aggregate+pool
// PERSISTENT WAVES: 8192 waves total (32/CU), each owns a contiguous node range
// (batch-sorted -> 1-2 graphs per wave; csrp reads sequential). Inner loop = R4
// structure: lane owns features {2n,2n+1} (dword), 16-deep register batch of
// shfl-broadcast (src,p) -> 16 independent row-gathers in flight, no spill.
// Graph-max pooled in registers, flushed on graph change (atomics ~1.2M not 6.4M).
__global__ __launch_bounds__(256, 8) void aggregate_kernel(
    const unsigned* __restrict__ h2u, const float* __restrict__ a_src,
    const float* __restrict__ a_dst, const int* __restrict__ rowstart,
    const uint2* __restrict__ csrp, const float* __restrict__ bias,
    const int* __restrict__ batch, float* __restrict__ out) {
    const int wid = threadIdx.x >> 6, lane = threadIdx.x & 63;
    const int w = blockIdx.x * 4 + wid;              // wave id in [0, AGG_WAVES)
    // contiguous node range for this wave
    const int q = N_NODES / AGG_WAVES;               // 6
    const int r = N_NODES - q * AGG_WAVES;           // 848
    int n0 = w * q + (w < r ? w : r);
    int n1 = n0 + q + (w < r ? 1 : 0);
    const float b0 = bias[2 * lane], b1 = bias[2 * lane + 1];

    int gcur = -1;
    float m0 = 0.f, m1 = 0.f;
    for (int n = n0; n < n1; ++n) {
        int rs = rowstart[n], re = rowstart[n + 1];
        float adn = a_dst[n];
        float pself = __expf(lrelu(a_src[n] + adn));
        float2 hv = bf2f(h2u[(size_t)n * 64 + lane]);
        float denom = pself;
        float2 acc = make_float2(pself * hv.x, pself * hv.y);
        for (int base = rs; base < re; base += 64) {
            int cnt = re - base; if (cnt > 64) cnt = 64;
            uint2 sp = make_uint2(0u, 0u);
            bool valid = (base + lane < re);
            if (valid) sp = csrp[base + lane];
            float pe = valid ? __expf(lrelu(__uint_as_float(sp.y) + adn)) : 0.f;
            float ds = pe;
            for (int o = 32; o; o >>= 1) ds += __shfl_xor(ds, o);
            denom += ds;
            int e = 0;
            for (; e + 16 <= cnt; e += 16) {
                unsigned uu[16]; float pp[16];
#pragma unroll
                for (int i = 0; i < 16; ++i) {
                    unsigned src = (unsigned)__shfl((int)sp.x, e + i);
                    pp[i] = __shfl(pe, e + i);
                    uu[i] = h2u[(size_t)src * 64 + lane];
                }
#pragma unroll
                for (int i = 0; i < 16; ++i) {
                    float2 g = bf2f(uu[i]);
                    acc.x = fmaf(pp[i], g.x, acc.x);
                    acc.y = fmaf(pp[i], g.y, acc.y);
                }
            }
            {   // remainder (< 16): full-wave shfl, batched loads
                unsigned uu2[15]; float pp2[15];
                int rem = cnt - e;
#pragma unroll
                for (int i = 0; i < 15; ++i) {
                    if (i < rem) {
                        unsigned src = (unsigned)__shfl((int)sp.x, e + i);
                        pp2[i] = __shfl(pe, e + i);
                        uu2[i] = h2u[(size_t)src * 64 + lane];
                    }
                }
#pragma unroll
                for (int i = 0; i < 15; ++i) {
                    if (i < rem) {
                        float2 g = bf2f(uu2[i]);
                        acc.x = fmaf(pp2[i], g.x, acc.x);
                        acc.y = fmaf(pp2[i], g.y, acc.y);
                    }
                }
            }
        }
        float inv = 1.0f / denom;
        float o0 = fmaxf(acc.x * inv + b0, 0.0f);
        float o1 = fmaxf(acc.y * inv + b1, 0.0f);
        int g = batch[n];                            // wave-uniform branch (sorted batch)
        if (g != gcur) {
            if (gcur >= 0) {
                unsigned* outp = (unsigned*)(out + (size_t)gcur * HID);
                atomicMax(&outp[2 * lane], __float_as_uint(m0));
                atomicMax(&outp[2 * lane + 1], __float_as_uint(m1));
            }
            gcur = g; m0 = o0; m1 = o1;
        } else {
            m0 = fmaxf(m0, o0); m1 = fmaxf(m1, o1);
        }
    }
    if (gcur >= 0) {
        unsigned* outp = (unsigned*)(out + (size_t)gcur * HID);
        atomicMax(&outp[2 * lane], __float_as_uint(m0));
        atomicMax(&outp[2 * lane + 1], __float_as_uint(m1));
    }
}

// ---------------------------------------------------------------- launch
extern "C" void kernel_launch(void* const* d_in, const int* in_sizes, int n_in,
                              void* d_out, int out_size, void* d_ws, size_t ws_size,
                              hipStream_t stream) {
    const float* x     = (const float*)d_in[0];
    const float* W     = (const float*)d_in[1];
    const float* att_s = (const float*)d_in[2];
    const float* att_d = (const float*)d_in[3];
    const float* bias  = (const float*)d_in[4];
    const int*   ei    = (const int*)d_in[5];
    const int*   batch = (const int*)d_in[6];
    float*       out   = (float*)d_out;

    char* ws = (char*)d_ws;
    size_t off = 0;
    auto alloc = [&](size_t bytes) -> void* {
        void* p = ws + off;
        off += (bytes + 255) & ~(size_t)255;
        return p;
    };
    const int NB = (N_NODES + 1023) / 1024;   // 49
    __bf16* h2       = (__bf16*)alloc((size_t)N_NODES * HID * 2);
    __bf16* wt       = (__bf16*)alloc((size_t)HID * IN_DIM * 2);
    float*  a_src    = (float*)alloc((size_t)N_NODES * 4);
    float*  a_dst    = (float*)alloc((size_t)N_NODES * 4);
    int*    deg      = (int*)alloc((size_t)N_NODES * 4);
    int*    rowstart = (int*)alloc((size_t)(N_NODES + 1) * 4);
    int*    bsum     = (int*)alloc((size_t)NB * 4);
    int*    boff     = (int*)alloc((size_t)NB * 4);
    uint2*  csrp     = (uint2*)alloc((size_t)N_EDGES * 8);
    (void)ws_size; (void)in_sizes; (void)n_in;

    int init_n = (N_NODES > out_size ? N_NODES : out_size);
    hipLaunchKernelGGL(init_kernel, dim3((init_n + 255) / 256), dim3(256), 0, stream,
                       deg, out, out_size);
    hipLaunchKernelGGL(wtrans_kernel, dim3((HID * IN_DIM) / 256), dim3(256), 0, stream,
                       W, wt);
    hipLaunchKernelGGL(gemm_kernel, dim3((N_NODES + 127) / 128), dim3(256), 0, stream,
                       x, wt, h2, att_s, att_d, a_src, a_dst);
    hipLaunchKernelGGL(hist_kernel, dim3((N_EDGES + 255) / 256), dim3(256), 0, stream,
                       ei, deg);
    hipLaunchKernelGGL(scan1_kernel, dim3(NB), dim3(256), 0, stream, deg, bsum);
    hipLaunchKernelGGL(scan2_kernel, dim3(1), dim3(64), 0, stream, bsum, boff, rowstart, NB);
    hipLaunchKernelGGL(scan3_kernel, dim3(NB), dim3(256), 0, stream, deg, boff, rowstart);
    hipLaunchKernelGGL(scatter_kernel, dim3((N_EDGES + 255) / 256), dim3(256), 0, stream,
                       ei, rowstart, deg, csrp, a_src);
    hipLaunchKernelGGL(aggregate_kernel, dim3(AGG_WAVES / 4), dim3(256), 0, stream,
                       (const unsigned*)h2, a_src, a_dst, rowstart, csrp, bias, batch, out);
}

// Round 8
// 570.765 us; speedup vs baseline: 1.4136x; 1.2501x over previous
//
#include <hip/hip_runtime.h>
#include <hip/hip_bf16.h>

#define N_NODES 50000
#define N_EDGES 1600000
#define IN_DIM 1024
#define HID 128
#define AGG_WAVES 6144          // 1536 blocks x 4 waves = 24 waves/CU at launch_bounds(256,6)

typedef __bf16 bf16x8 __attribute__((ext_vector_type(8)));
typedef float f32x4 __attribute__((ext_vector_type(4)));
typedef __bf16 bf16x4 __attribute__((ext_vector_type(4)));

// bf16-pair (packed in uint) -> 2 floats (features 2l = low, 2l+1 = high)
__device__ __forceinline__ float2 bf2f(unsigned u) {
    return make_float2(__uint_as_float(u << 16), __uint_as_float(u & 0xffff0000u));
}
__device__ __forceinline__ float lrelu(float v) { return v > 0.f ? v : 0.2f * v; }

// ---------------------------------------------------------------- init
__global__ void init_kernel(int* __restrict__ deg, float* __restrict__ out, int out_n) {
    int i = blockIdx.x * 256 + threadIdx.x;
    if (i < N_NODES) deg[i] = 0;
    if (i < out_n) out[i] = 0.0f;
}

// ---------------------------------------------------------------- W^T -> bf16  (wt[n][k], 128x1024)
__global__ void wtrans_kernel(const float* __restrict__ W, __bf16* __restrict__ wt) {
    int i = blockIdx.x * 256 + threadIdx.x;
    int n = i >> 10, k = i & 1023;
    wt[i] = (__bf16)W[(size_t)k * HID + n];
}

// ---------------------------------------------------------------- GEMM h = x @ W (bf16 MFMA)
// + fused att epilogue: a_src/a_dst from fp32 acc fragments (16-lane shfl reduce).
__global__ __launch_bounds__(256) void gemm_kernel(const float* __restrict__ x,
                                                   const __bf16* __restrict__ wt,
                                                   __bf16* __restrict__ h2,
                                                   const float* __restrict__ att_s,
                                                   const float* __restrict__ att_d,
                                                   float* __restrict__ o_as,
                                                   float* __restrict__ o_ad) {
    __shared__ __bf16 xa[128][40];
    __shared__ __bf16 wb[128][40];
    const int t = threadIdx.x;
    const int m0 = blockIdx.x * 128;
    const int wid = t >> 6, lane = t & 63;
    const int lm = lane & 15, q8 = (lane >> 4) * 8;
    const int rw0 = wid * 32;

    f32x4 acc[2][8] = {};
    for (int k0 = 0; k0 < IN_DIM; k0 += 32) {
#pragma unroll
        for (int l = 0; l < 4; ++l) {
            int f = t + l * 256;
            int row = f >> 3, kq = f & 7;
            int gr = m0 + row;
            float4 v = make_float4(0.f, 0.f, 0.f, 0.f);
            if (gr < N_NODES)
                v = *(const float4*)(x + (size_t)gr * IN_DIM + k0 + kq * 4);
            bf16x4 b; b[0] = (__bf16)v.x; b[1] = (__bf16)v.y; b[2] = (__bf16)v.z; b[3] = (__bf16)v.w;
            *(bf16x4*)&xa[row][kq * 4] = b;
        }
#pragma unroll
        for (int l = 0; l < 4; ++l) {
            int f = t + l * 256;
            int n = f >> 3, c = f & 7;
            *(uint2*)&wb[n][c * 4] = *(const uint2*)(wt + (size_t)n * IN_DIM + k0 + c * 4);
        }
        __syncthreads();
        bf16x8 af0 = *(const bf16x8*)&xa[rw0 + lm][q8];
        bf16x8 af1 = *(const bf16x8*)&xa[rw0 + 16 + lm][q8];
#pragma unroll
        for (int ct = 0; ct < 8; ++ct) {
            bf16x8 bfr = *(const bf16x8*)&wb[ct * 16 + lm][q8];
            acc[0][ct] = __builtin_amdgcn_mfma_f32_16x16x32_bf16(af0, bfr, acc[0][ct], 0, 0, 0);
            acc[1][ct] = __builtin_amdgcn_mfma_f32_16x16x32_bf16(af1, bfr, acc[1][ct], 0, 0, 0);
        }
        __syncthreads();
    }
    const int quad = lane >> 4;
    float attsf[8], attdf[8];
#pragma unroll
    for (int ct = 0; ct < 8; ++ct) {
        attsf[ct] = att_s[ct * 16 + lm];
        attdf[ct] = att_d[ct * 16 + lm];
    }
#pragma unroll
    for (int rt = 0; rt < 2; ++rt) {
#pragma unroll
        for (int reg = 0; reg < 4; ++reg) {
            int row = m0 + rw0 + rt * 16 + quad * 4 + reg;
            float ps = 0.f, pd = 0.f;
#pragma unroll
            for (int ct = 0; ct < 8; ++ct) {
                float v = acc[rt][ct][reg];
                ps = fmaf(v, attsf[ct], ps);
                pd = fmaf(v, attdf[ct], pd);
            }
#pragma unroll
            for (int o = 8; o; o >>= 1) {
                ps += __shfl_xor(ps, o);
                pd += __shfl_xor(pd, o);
            }
            if (row < N_NODES) {
                if (lm == 0) { o_as[row] = ps; o_ad[row] = pd; }
#pragma unroll
                for (int ct = 0; ct < 8; ++ct)
                    h2[(size_t)row * HID + ct * 16 + lm] = (__bf16)acc[rt][ct][reg];
            }
        }
    }
}

// ---------------------------------------------------------------- CSR build
__global__ void hist_kernel(const int* __restrict__ ei, int* __restrict__ deg) {
    int e = blockIdx.x * 256 + threadIdx.x;
    if (e < N_EDGES) atomicAdd(&deg[ei[N_EDGES + e]], 1);
}

__global__ void scan1_kernel(const int* __restrict__ deg, int* __restrict__ bsum) {
    int b = blockIdx.x, t = threadIdx.x;
    int base = b * 1024 + t * 4;
    int s = 0;
#pragma unroll
    for (int j = 0; j < 4; ++j) {
        int idx = base + j;
        if (idx < N_NODES) s += deg[idx];
    }
    for (int o = 32; o; o >>= 1) s += __shfl_xor(s, o);
    __shared__ int wsum[4];
    int lane = t & 63, w = t >> 6;
    if (lane == 0) wsum[w] = s;
    __syncthreads();
    if (t == 0) bsum[b] = wsum[0] + wsum[1] + wsum[2] + wsum[3];
}

__global__ void scan2_kernel(const int* __restrict__ bsum, int* __restrict__ boff,
                             int* __restrict__ rowstart, int nb) {
    if (threadIdx.x == 0 && blockIdx.x == 0) {
        int run = 0;
        for (int i = 0; i < nb; ++i) { boff[i] = run; run += bsum[i]; }
        rowstart[N_NODES] = run;
    }
}

__global__ void scan3_kernel(int* __restrict__ deg, const int* __restrict__ boff,
                             int* __restrict__ rowstart) {
    int b = blockIdx.x, t = threadIdx.x;
    int base = b * 1024 + t * 4;
    int v[4]; int s = 0;
#pragma unroll
    for (int j = 0; j < 4; ++j) {
        int idx = base + j;
        v[j] = (idx < N_NODES) ? deg[idx] : 0;
        s += v[j];
    }
    int lane = t & 63, w = t >> 6;
    int inc = s;
    for (int o = 1; o < 64; o <<= 1) {
        int u = __shfl_up(inc, o);
        if (lane >= o) inc += u;
    }
    __shared__ int wt[4];
    if (lane == 63) wt[w] = inc;
    __syncthreads();
    int woff = 0;
    for (int i = 0; i < w; ++i) woff += wt[i];
    int run = woff + inc - s + boff[b];
#pragma unroll
    for (int j = 0; j < 4; ++j) {
        int idx = base + j;
        if (idx < N_NODES) {
            rowstart[idx] = run;
            run += v[j];
            deg[idx] = 0;   // re-zero: reused as scatter cursor
        }
    }
}

// scatter: CSR slot gets (src, a_src[src]); a_dst folded in at aggregate (wave-uniform).
__global__ void scatter_kernel(const int* __restrict__ ei, const int* __restrict__ rowstart,
                               int* __restrict__ cursor, uint2* __restrict__ csrp,
                               const float* __restrict__ a_src) {
    int e = blockIdx.x * 256 + threadIdx.x;
    if (e >= N_EDGES) return;
    int s = ei[e], d = ei[N_EDGES + e];
    int pos = atomicAdd(&cursor[d], 1);
    uint2 v; v.x = (unsigned)s; v.y = __float_as_uint(a_src[s]);
    csrp[rowstart[d] + pos] = v;
}

// ---------------------------------------------------------------- aggregate+pool
// PERSISTENT WAVES: 6144 waves (24/CU at launch_bounds(256,6) -> VGPR cap 85,
// comfortably above the ~60 the 16-deep batch needs: NO SPILL, unlike (256,8)
// whose 64-reg cap spilled 800 MB of scratch traffic in R7).
// Inner loop: lane owns features {2n,2n+1} (dword); 16-deep register batch of
// shfl-broadcast (src,p) -> 16 independent row-gathers in flight. Invalid lanes
// carry (src=0, p=0) so the last batch runs full-width with zero-weight padding
// (row-0 gathers, L1-hit, free) -- no remainder path, less reg pressure.
// Graph-max pooled in registers, flushed on graph change (atomics ~1.2M not 6.4M).
__global__ __launch_bounds__(256, 6) void aggregate_kernel(
    const unsigned* __restrict__ h2u, const float* __restrict__ a_src,
    const float* __restrict__ a_dst, const int* __restrict__ rowstart,
    const uint2* __restrict__ csrp, const float* __restrict__ bias,
    const int* __restrict__ batch, float* __restrict__ out) {
    const int wid = threadIdx.x >> 6, lane = threadIdx.x & 63;
    const int w = blockIdx.x * 4 + wid;              // wave id in [0, AGG_WAVES)
    const int q = N_NODES / AGG_WAVES;               // 8
    const int r = N_NODES - q * AGG_WAVES;           // 848
    int n0 = w * q + (w < r ? w : r);
    int n1 = n0 + q + (w < r ? 1 : 0);
    const float b0 = bias[2 * lane], b1 = bias[2 * lane + 1];

    int gcur = -1;
    float m0 = 0.f, m1 = 0.f;
    for (int n = n0; n < n1; ++n) {
        int rs = rowstart[n], re = rowstart[n + 1];
        float adn = a_dst[n];
        float pself = __expf(lrelu(a_src[n] + adn));
        float2 hv = bf2f(h2u[(size_t)n * 64 + lane]);
        float denom = pself;
        float2 acc = make_float2(pself * hv.x, pself * hv.y);
        for (int base = rs; base < re; base += 64) {
            int cnt = re - base; if (cnt > 64) cnt = 64;
            uint2 sp = make_uint2(0u, 0u);
            bool valid = (base + lane < re);
            if (valid) sp = csrp[base + lane];
            float pe = valid ? __expf(lrelu(__uint_as_float(sp.y) + adn)) : 0.f;
            float ds = pe;
            for (int o = 32; o; o >>= 1) ds += __shfl_xor(ds, o);
            denom += ds;
            for (int e = 0; e < cnt; e += 16) {
                unsigned uu[16]; float pp[16];
#pragma unroll
                for (int i = 0; i < 16; ++i) {
                    unsigned src = (unsigned)__shfl((int)sp.x, e + i);
                    pp[i] = __shfl(pe, e + i);
                    uu[i] = h2u[(size_t)src * 64 + lane];
                }
#pragma unroll
                for (int i = 0; i < 16; ++i) {
                    float2 g = bf2f(uu[i]);
                    acc.x = fmaf(pp[i], g.x, acc.x);
                    acc.y = fmaf(pp[i], g.y, acc.y);
                }
            }
        }
        float inv = 1.0f / denom;
        float o0 = fmaxf(acc.x * inv + b0, 0.0f);
        float o1 = fmaxf(acc.y * inv + b1, 0.0f);
        int g = batch[n];                            // wave-uniform branch (sorted batch)
        if (g != gcur) {
            if (gcur >= 0) {
                unsigned* outp = (unsigned*)(out + (size_t)gcur * HID);
                atomicMax(&outp[2 * lane], __float_as_uint(m0));
                atomicMax(&outp[2 * lane + 1], __float_as_uint(m1));
            }
            gcur = g; m0 = o0; m1 = o1;
        } else {
            m0 = fmaxf(m0, o0); m1 = fmaxf(m1, o1);
        }
    }
    if (gcur >= 0) {
        unsigned* outp = (unsigned*)(out + (size_t)gcur * HID);
        atomicMax(&outp[2 * lane], __float_as_uint(m0));
        atomicMax(&outp[2 * lane + 1], __float_as_uint(m1));
    }
}

// ---------------------------------------------------------------- launch
extern "C" void kernel_launch(void* const* d_in, const int* in_sizes, int n_in,
                              void* d_out, int out_size, void* d_ws, size_t ws_size,
                              hipStream_t stream) {
    const float* x     = (const float*)d_in[0];
    const float* W     = (const float*)d_in[1];
    const float* att_s = (const float*)d_in[2];
    const float* att_d = (const float*)d_in[3];
    const float* bias  = (const float*)d_in[4];
    const int*   ei    = (const int*)d_in[5];
    const int*   batch = (const int*)d_in[6];
    float*       out   = (float*)d_out;

    char* ws = (char*)d_ws;
    size_t off = 0;
    auto alloc = [&](size_t bytes) -> void* {
        void* p = ws + off;
        off += (bytes + 255) & ~(size_t)255;
        return p;
    };
    const int NB = (N_NODES + 1023) / 1024;   // 49
    __bf16* h2       = (__bf16*)alloc((size_t)N_NODES * HID * 2);
    __bf16* wt       = (__bf16*)alloc((size_t)HID * IN_DIM * 2);
    float*  a_src    = (float*)alloc((size_t)N_NODES * 4);
    float*  a_dst    = (float*)alloc((size_t)N_NODES * 4);
    int*    deg      = (int*)alloc((size_t)N_NODES * 4);
    int*    rowstart = (int*)alloc((size_t)(N_NODES + 1) * 4);
    int*    bsum     = (int*)alloc((size_t)NB * 4);
    int*    boff     = (int*)alloc((size_t)NB * 4);
    uint2*  csrp     = (uint2*)alloc((size_t)N_EDGES * 8);
    (void)ws_size; (void)in_sizes; (void)n_in;

    int init_n = (N_NODES > out_size ? N_NODES : out_size);
    hipLaunchKernelGGL(init_kernel, dim3((init_n + 255) / 256), dim3(256), 0, stream,
                       deg, out, out_size);
    hipLaunchKernelGGL(wtrans_kernel, dim3((HID * IN_DIM) / 256), dim3(256), 0, stream,
                       W, wt);
    hipLaunchKernelGGL(gemm_kernel, dim3((N_NODES + 127) / 128), dim3(256), 0, stream,
                       x, wt, h2, att_s, att_d, a_src, a_dst);
    hipLaunchKernelGGL(hist_kernel, dim3((N_EDGES + 255) / 256), dim3(256), 0, stream,
                       ei, deg);
    hipLaunchKernelGGL(scan1_kernel, dim3(NB), dim3(256), 0, stream, deg, bsum);
    hipLaunchKernelGGL(scan2_kernel, dim3(1), dim3(64), 0, stream, bsum, boff, rowstart, NB);
    hipLaunchKernelGGL(scan3_kernel, dim3(NB), dim3(256), 0, stream, deg, boff, rowstart);
    hipLaunchKernelGGL(scatter_kernel, dim3((N_EDGES + 255) / 256), dim3(256), 0, stream,
                       ei, rowstart, deg, csrp, a_src);
    hipLaunchKernelGGL(aggregate_kernel, dim3(AGG_WAVES / 4), dim3(256), 0, stream,
                       (const unsigned*)h2, a_src, a_dst, rowstart, csrp, bias, batch, out);
}

// Round 9
// 540.073 us; speedup vs baseline: 1.4939x; 1.0568x over previous
//
#include <hip/hip_runtime.h>
#include <hip/hip_bf16.h>

#define N_NODES 50000
#define N_EDGES 1600000
#define IN_DIM 1024
#define HID 128
#define AGG_WAVES 6144          // 1536 blocks x 4 waves = 24 waves/CU at launch_bounds(256,6)

typedef __bf16 bf16x8 __attribute__((ext_vector_type(8)));
typedef float f32x4 __attribute__((ext_vector_type(4)));
typedef __bf16 bf16x4 __attribute__((ext_vector_type(4)));

// bf16-pair (packed in uint) -> 2 floats (features 2l = low, 2l+1 = high)
__device__ __forceinline__ float2 bf2f(unsigned u) {
    return make_float2(__uint_as_float(u << 16), __uint_as_float(u & 0xffff0000u));
}
__device__ __forceinline__ float lrelu(float v) { return v > 0.f ? v : 0.2f * v; }

// ---------------------------------------------------------------- prep: zero deg/out + W^T->bf16
__global__ void prep_kernel(const float* __restrict__ W, __bf16* __restrict__ wt,
                            int* __restrict__ deg, float* __restrict__ out, int out_n) {
    int i = blockIdx.x * 256 + threadIdx.x;       // grid covers 131072
    if (i < N_NODES) deg[i] = 0;
    if (i < out_n) out[i] = 0.0f;
    if (i < HID * IN_DIM) {
        int n = i >> 10, k = i & 1023;
        wt[i] = (__bf16)W[(size_t)k * HID + n];
    }
}

// ---------------------------------------------------------------- GEMM h = x @ W (bf16 MFMA)
// BM=64 x BN=128 (full HID), BK=32 -> 782 blocks (~3/CU, vs 391 @BM=128 which
// capped occupancy at 16%). Register-prefetch pipeline: next tile's global loads
// issue BEFORE the MFMA on the current tile, so HBM latency hides behind compute
// + barrier instead of stalling the loop head. Single LDS buffer (15 KB).
// + fused att epilogue: a_src/a_dst from fp32 acc fragments (16-lane shfl reduce).
__global__ __launch_bounds__(256) void gemm_kernel(const float* __restrict__ x,
                                                   const __bf16* __restrict__ wt,
                                                   __bf16* __restrict__ h2,
                                                   const float* __restrict__ att_s,
                                                   const float* __restrict__ att_d,
                                                   float* __restrict__ o_as,
                                                   float* __restrict__ o_ad) {
    __shared__ __bf16 xa[64][40];
    __shared__ __bf16 wb[128][40];
    const int t = threadIdx.x;
    const int m0 = blockIdx.x * 64;
    const int wid = t >> 6, lane = t & 63;
    const int lm = lane & 15, q8 = (lane >> 4) * 8;
    const int rw0 = wid * 16;

    // staging decode (constant per thread)
    const int xrow = t >> 2, xkq = (t & 3);       // 256 threads x2: x has 64 rows x 8 kq slots
    const int wn = t >> 1, wc2 = (t & 1);         // wb: 128 rows x 8 c slots, x4

    float4 xs_reg[2];
    uint2  ws_reg[4];

    auto stage_regs = [&](int k0) {
#pragma unroll
        for (int l = 0; l < 2; ++l) {
            int f = t + l * 256;
            int row = f >> 3, kq = f & 7;
            int gr = m0 + row;
            float4 v = make_float4(0.f, 0.f, 0.f, 0.f);
            if (gr < N_NODES)
                v = *(const float4*)(x + (size_t)gr * IN_DIM + k0 + kq * 4);
            xs_reg[l] = v;
        }
#pragma unroll
        for (int l = 0; l < 4; ++l) {
            int f = t + l * 256;
            int n = f >> 3, c = f & 7;
            ws_reg[l] = *(const uint2*)(wt + (size_t)n * IN_DIM + k0 + c * 4);
        }
    };
    auto regs_to_lds = [&]() {
#pragma unroll
        for (int l = 0; l < 2; ++l) {
            int f = t + l * 256;
            int row = f >> 3, kq = f & 7;
            bf16x4 b;
            b[0] = (__bf16)xs_reg[l].x; b[1] = (__bf16)xs_reg[l].y;
            b[2] = (__bf16)xs_reg[l].z; b[3] = (__bf16)xs_reg[l].w;
            *(bf16x4*)&xa[row][kq * 4] = b;
        }
#pragma unroll
        for (int l = 0; l < 4; ++l) {
            int f = t + l * 256;
            int n = f >> 3, c = f & 7;
            *(uint2*)&wb[n][c * 4] = ws_reg[l];
        }
    };

    f32x4 acc[8] = {};
    stage_regs(0);
    regs_to_lds();
    __syncthreads();
    for (int it = 0; it < 32; ++it) {
        if (it + 1 < 32) stage_regs((it + 1) * 32);   // global loads in flight during MFMA
        bf16x8 af = *(const bf16x8*)&xa[rw0 + lm][q8];
#pragma unroll
        for (int ct = 0; ct < 8; ++ct) {
            bf16x8 bfr = *(const bf16x8*)&wb[ct * 16 + lm][q8];
            acc[ct] = __builtin_amdgcn_mfma_f32_16x16x32_bf16(af, bfr, acc[ct], 0, 0, 0);
        }
        if (it + 1 < 32) {
            __syncthreads();          // all reads of this tile done
            regs_to_lds();            // overwrite with next tile
            __syncthreads();          // writes visible
        }
    }
    // epilogue: C/D layout col=lane&15, row=(lane>>4)*4+reg ; fused att dots
    const int quad = lane >> 4;
    float attsf[8], attdf[8];
#pragma unroll
    for (int ct = 0; ct < 8; ++ct) {
        attsf[ct] = att_s[ct * 16 + lm];
        attdf[ct] = att_d[ct * 16 + lm];
    }
#pragma unroll
    for (int reg = 0; reg < 4; ++reg) {
        int row = m0 + rw0 + quad * 4 + reg;
        float ps = 0.f, pd = 0.f;
#pragma unroll
        for (int ct = 0; ct < 8; ++ct) {
            float v = acc[ct][reg];
            ps = fmaf(v, attsf[ct], ps);
            pd = fmaf(v, attdf[ct], pd);
        }
#pragma unroll
        for (int o = 8; o; o >>= 1) {
            ps += __shfl_xor(ps, o);
            pd += __shfl_xor(pd, o);
        }
        if (row < N_NODES) {
            if (lm == 0) { o_as[row] = ps; o_ad[row] = pd; }
#pragma unroll
            for (int ct = 0; ct < 8; ++ct)
                h2[(size_t)row * HID + ct * 16 + lm] = (__bf16)acc[ct][reg];
        }
    }
    (void)xrow; (void)xkq; (void)wn; (void)wc2;
}

// ---------------------------------------------------------------- CSR build
__global__ void hist_kernel(const int* __restrict__ ei, int* __restrict__ deg) {
    int e = blockIdx.x * 256 + threadIdx.x;
    if (e < N_EDGES) atomicAdd(&deg[ei[N_EDGES + e]], 1);
}

__global__ void scan1_kernel(const int* __restrict__ deg, int* __restrict__ bsum) {
    int b = blockIdx.x, t = threadIdx.x;
    int base = b * 1024 + t * 4;
    int s = 0;
#pragma unroll
    for (int j = 0; j < 4; ++j) {
        int idx = base + j;
        if (idx < N_NODES) s += deg[idx];
    }
    for (int o = 32; o; o >>= 1) s += __shfl_xor(s, o);
    __shared__ int wsum[4];
    int lane = t & 63, w = t >> 6;
    if (lane == 0) wsum[w] = s;
    __syncthreads();
    if (t == 0) bsum[b] = wsum[0] + wsum[1] + wsum[2] + wsum[3];
}

__global__ void scan2_kernel(const int* __restrict__ bsum, int* __restrict__ boff,
                             int* __restrict__ rowstart, int nb) {
    if (threadIdx.x == 0 && blockIdx.x == 0) {
        int run = 0;
        for (int i = 0; i < nb; ++i) { boff[i] = run; run += bsum[i]; }
        rowstart[N_NODES] = run;
    }
}

__global__ void scan3_kernel(int* __restrict__ deg, const int* __restrict__ boff,
                             int* __restrict__ rowstart) {
    int b = blockIdx.x, t = threadIdx.x;
    int base = b * 1024 + t * 4;
    int v[4]; int s = 0;
#pragma unroll
    for (int j = 0; j < 4; ++j) {
        int idx = base + j;
        v[j] = (idx < N_NODES) ? deg[idx] : 0;
        s += v[j];
    }
    int lane = t & 63, w = t >> 6;
    int inc = s;
    for (int o = 1; o < 64; o <<= 1) {
        int u = __shfl_up(inc, o);
        if (lane >= o) inc += u;
    }
    __shared__ int wt[4];
    if (lane == 63) wt[w] = inc;
    __syncthreads();
    int woff = 0;
    for (int i = 0; i < w; ++i) woff += wt[i];
    int run = woff + inc - s + boff[b];
#pragma unroll
    for (int j = 0; j < 4; ++j) {
        int idx = base + j;
        if (idx < N_NODES) {
            rowstart[idx] = run;
            run += v[j];
            deg[idx] = 0;   // re-zero: reused as scatter cursor
        }
    }
}

// scatter: CSR slot gets (src, a_src[src]); a_dst folded in at aggregate (wave-uniform).
__global__ void scatter_kernel(const int* __restrict__ ei, const int* __restrict__ rowstart,
                               int* __restrict__ cursor, uint2* __restrict__ csrp,
                               const float* __restrict__ a_src) {
    int e = blockIdx.x * 256 + threadIdx.x;
    if (e >= N_EDGES) return;
    int s = ei[e], d = ei[N_EDGES + e];
    int pos = atomicAdd(&cursor[d], 1);
    uint2 v; v.x = (unsigned)s; v.y = __float_as_uint(a_src[s]);
    csrp[rowstart[d] + pos] = v;
}

// ---------------------------------------------------------------- aggregate+pool
// PERSISTENT WAVES: 6144 waves (24/CU at launch_bounds(256,6), VGPR cap 85 -> no
// spill). Lane owns features {2n,2n+1}; 16-deep register batch of shfl-broadcast
// (src,p) -> 16 independent row-gathers in flight. Invalid lanes carry (0,0) so
// the last batch runs full-width with zero-weight row-0 gathers (L1-hit, free).
// Graph-max pooled in registers, flushed on graph change.
__global__ __launch_bounds__(256, 6) void aggregate_kernel(
    const unsigned* __restrict__ h2u, const float* __restrict__ a_src,
    const float* __restrict__ a_dst, const int* __restrict__ rowstart,
    const uint2* __restrict__ csrp, const float* __restrict__ bias,
    const int* __restrict__ batch, float* __restrict__ out) {
    const int wid = threadIdx.x >> 6, lane = threadIdx.x & 63;
    const int w = blockIdx.x * 4 + wid;
    const int q = N_NODES / AGG_WAVES;
    const int r = N_NODES - q * AGG_WAVES;
    int n0 = w * q + (w < r ? w : r);
    int n1 = n0 + q + (w < r ? 1 : 0);
    const float b0 = bias[2 * lane], b1 = bias[2 * lane + 1];

    int gcur = -1;
    float m0 = 0.f, m1 = 0.f;
    for (int n = n0; n < n1; ++n) {
        int rs = rowstart[n], re = rowstart[n + 1];
        float adn = a_dst[n];
        float pself = __expf(lrelu(a_src[n] + adn));
        float2 hv = bf2f(h2u[(size_t)n * 64 + lane]);
        float denom = pself;
        float2 acc = make_float2(pself * hv.x, pself * hv.y);
        for (int base = rs; base < re; base += 64) {
            int cnt = re - base; if (cnt > 64) cnt = 64;
            uint2 sp = make_uint2(0u, 0u);
            bool valid = (base + lane < re);
            if (valid) sp = csrp[base + lane];
            float pe = valid ? __expf(lrelu(__uint_as_float(sp.y) + adn)) : 0.f;
            float ds = pe;
            for (int o = 32; o; o >>= 1) ds += __shfl_xor(ds, o);
            denom += ds;
            for (int e = 0; e < cnt; e += 16) {
                unsigned uu[16]; float pp[16];
#pragma unroll
                for (int i = 0; i < 16; ++i) {
                    unsigned src = (unsigned)__shfl((int)sp.x, e + i);
                    pp[i] = __shfl(pe, e + i);
                    uu[i] = h2u[(size_t)src * 64 + lane];
                }
#pragma unroll
                for (int i = 0; i < 16; ++i) {
                    float2 g = bf2f(uu[i]);
                    acc.x = fmaf(pp[i], g.x, acc.x);
                    acc.y = fmaf(pp[i], g.y, acc.y);
                }
            }
        }
        float inv = 1.0f / denom;
        float o0 = fmaxf(acc.x * inv + b0, 0.0f);
        float o1 = fmaxf(acc.y * inv + b1, 0.0f);
        int g = batch[n];
        if (g != gcur) {
            if (gcur >= 0) {
                unsigned* outp = (unsigned*)(out + (size_t)gcur * HID);
                atomicMax(&outp[2 * lane], __float_as_uint(m0));
                atomicMax(&outp[2 * lane + 1], __float_as_uint(m1));
            }
            gcur = g; m0 = o0; m1 = o1;
        } else {
            m0 = fmaxf(m0, o0); m1 = fmaxf(m1, o1);
        }
    }
    if (gcur >= 0) {
        unsigned* outp = (unsigned*)(out + (size_t)gcur * HID);
        atomicMax(&outp[2 * lane], __float_as_uint(m0));
        atomicMax(&outp[2 * lane + 1], __float_as_uint(m1));
    }
}

// ---------------------------------------------------------------- launch
extern "C" void kernel_launch(void* const* d_in, const int* in_sizes, int n_in,
                              void* d_out, int out_size, void* d_ws, size_t ws_size,
                              hipStream_t stream) {
    const float* x     = (const float*)d_in[0];
    const float* W     = (const float*)d_in[1];
    const float* att_s = (const float*)d_in[2];
    const float* att_d = (const float*)d_in[3];
    const float* bias  = (const float*)d_in[4];
    const int*   ei    = (const int*)d_in[5];
    const int*   batch = (const int*)d_in[6];
    float*       out   = (float*)d_out;

    char* ws = (char*)d_ws;
    size_t off = 0;
    auto alloc = [&](size_t bytes) -> void* {
        void* p = ws + off;
        off += (bytes + 255) & ~(size_t)255;
        return p;
    };
    const int NB = (N_NODES + 1023) / 1024;   // 49
    __bf16* h2       = (__bf16*)alloc((size_t)N_NODES * HID * 2);
    __bf16* wt       = (__bf16*)alloc((size_t)HID * IN_DIM * 2);
    float*  a_src    = (float*)alloc((size_t)N_NODES * 4);
    float*  a_dst    = (float*)alloc((size_t)N_NODES * 4);
    int*    deg      = (int*)alloc((size_t)N_NODES * 4);
    int*    rowstart = (int*)alloc((size_t)(N_NODES + 1) * 4);
    int*    bsum     = (int*)alloc((size_t)NB * 4);
    int*    boff     = (int*)alloc((size_t)NB * 4);
    uint2*  csrp     = (uint2*)alloc((size_t)N_EDGES * 8);
    (void)ws_size; (void)in_sizes; (void)n_in;

    hipLaunchKernelGGL(prep_kernel, dim3(512), dim3(256), 0, stream,
                       W, wt, deg, out, out_size);
    hipLaunchKernelGGL(gemm_kernel, dim3((N_NODES + 63) / 64), dim3(256), 0, stream,
                       x, wt, h2, att_s, att_d, a_src, a_dst);
    hipLaunchKernelGGL(hist_kernel, dim3((N_EDGES + 255) / 256), dim3(256), 0, stream,
                       ei, deg);
    hipLaunchKernelGGL(scan1_kernel, dim3(NB), dim3(256), 0, stream, deg, bsum);
    hipLaunchKernelGGL(scan2_kernel, dim3(1), dim3(64), 0, stream, bsum, boff, rowstart, NB);
    hipLaunchKernelGGL(scan3_kernel, dim3(NB), dim3(256), 0, stream, deg, boff, rowstart);
    hipLaunchKernelGGL(scatter_kernel, dim3((N_EDGES + 255) / 256), dim3(256), 0, stream,
                       ei, rowstart, deg, csrp, a_src);
    hipLaunchKernelGGL(aggregate_kernel, dim3(AGG_WAVES / 4), dim3(256), 0, stream,
                       (const unsigned*)h2, a_src, a_dst, rowstart, csrp, bias, batch, out);
}

// Round 10
// 507.488 us; speedup vs baseline: 1.5898x; 1.0642x over previous
//
#include <hip/hip_runtime.h>
#include <hip/hip_bf16.h>

#define N_NODES 50000
#define N_EDGES 1600000
#define IN_DIM 1024
#define HID 128
#define AGG_WAVES 6144          // 1536 blocks x 4 waves = 24 waves/CU at launch_bounds(256,6)

typedef __bf16 bf16x8 __attribute__((ext_vector_type(8)));
typedef float f32x4 __attribute__((ext_vector_type(4)));
typedef __bf16 bf16x4 __attribute__((ext_vector_type(4)));

// bf16-pair (packed in uint) -> 2 floats (features 2l = low, 2l+1 = high)
__device__ __forceinline__ float2 bf2f(unsigned u) {
    return make_float2(__uint_as_float(u << 16), __uint_as_float(u & 0xffff0000u));
}
__device__ __forceinline__ float lrelu(float v) { return v > 0.f ? v : 0.2f * v; }

// ---------------------------------------------------------------- prep: zero deg/out + W^T->bf16
__global__ void prep_kernel(const float* __restrict__ W, __bf16* __restrict__ wt,
                            int* __restrict__ deg, float* __restrict__ out, int out_n) {
    int i = blockIdx.x * 256 + threadIdx.x;       // grid covers 131072
    if (i < N_NODES) deg[i] = 0;
    if (i < out_n) out[i] = 0.0f;
    if (i < HID * IN_DIM) {
        int n = i >> 10, k = i & 1023;
        wt[i] = (__bf16)W[(size_t)k * HID + n];
    }
}

// ---------------------------------------------------------------- GEMM h = x @ W (bf16 MFMA)
// BM=64 x BN=128 (full HID), BK=32, 782 blocks. DOUBLE-BUFFERED LDS: MFMA reads
// buf[it&1] while regs_to_lds fills buf[it^1] -> ONE barrier per k-iter (R9 had
// two). Register prefetch: next tile's global loads issue before the MFMA so HBM
// latency hides behind compute+barrier. LDS 30 KB, VGPR ~84 (no spill).
// + fused att epilogue: a_src/a_dst from fp32 acc fragments (16-lane shfl reduce).
__global__ __launch_bounds__(256) void gemm_kernel(const float* __restrict__ x,
                                                   const __bf16* __restrict__ wt,
                                                   __bf16* __restrict__ h2,
                                                   const float* __restrict__ att_s,
                                                   const float* __restrict__ att_d,
                                                   float* __restrict__ o_as,
                                                   float* __restrict__ o_ad) {
    __shared__ __bf16 xa[2][64][40];
    __shared__ __bf16 wb[2][128][40];
    const int t = threadIdx.x;
    const int m0 = blockIdx.x * 64;
    const int wid = t >> 6, lane = t & 63;
    const int lm = lane & 15, q8 = (lane >> 4) * 8;
    const int rw0 = wid * 16;

    float4 xs_reg[2];
    uint2  ws_reg[4];

    auto stage_regs = [&](int k0) {
#pragma unroll
        for (int l = 0; l < 2; ++l) {
            int f = t + l * 256;
            int row = f >> 3, kq = f & 7;
            int gr = m0 + row;
            float4 v = make_float4(0.f, 0.f, 0.f, 0.f);
            if (gr < N_NODES)
                v = *(const float4*)(x + (size_t)gr * IN_DIM + k0 + kq * 4);
            xs_reg[l] = v;
        }
#pragma unroll
        for (int l = 0; l < 4; ++l) {
            int f = t + l * 256;
            int n = f >> 3, c = f & 7;
            ws_reg[l] = *(const uint2*)(wt + (size_t)n * IN_DIM + k0 + c * 4);
        }
    };
    auto regs_to_lds = [&](int b) {
#pragma unroll
        for (int l = 0; l < 2; ++l) {
            int f = t + l * 256;
            int row = f >> 3, kq = f & 7;
            bf16x4 v;
            v[0] = (__bf16)xs_reg[l].x; v[1] = (__bf16)xs_reg[l].y;
            v[2] = (__bf16)xs_reg[l].z; v[3] = (__bf16)xs_reg[l].w;
            *(bf16x4*)&xa[b][row][kq * 4] = v;
        }
#pragma unroll
        for (int l = 0; l < 4; ++l) {
            int f = t + l * 256;
            int n = f >> 3, c = f & 7;
            *(uint2*)&wb[b][n][c * 4] = ws_reg[l];
        }
    };

    f32x4 acc[8] = {};
    stage_regs(0);
    regs_to_lds(0);
    __syncthreads();
    for (int it = 0; it < 32; ++it) {
        const int cur = it & 1;
        if (it + 1 < 32) stage_regs((it + 1) * 32);   // global loads in flight during MFMA
        bf16x8 af = *(const bf16x8*)&xa[cur][rw0 + lm][q8];
#pragma unroll
        for (int ct = 0; ct < 8; ++ct) {
            bf16x8 bfr = *(const bf16x8*)&wb[cur][ct * 16 + lm][q8];
            acc[ct] = __builtin_amdgcn_mfma_f32_16x16x32_bf16(af, bfr, acc[ct], 0, 0, 0);
        }
        if (it + 1 < 32) {
            regs_to_lds(cur ^ 1);     // write OTHER buffer: no read-write conflict
            __syncthreads();          // make writes visible for next iter's reads
        }
    }
    // epilogue: C/D layout col=lane&15, row=(lane>>4)*4+reg ; fused att dots
    const int quad = lane >> 4;
    float attsf[8], attdf[8];
#pragma unroll
    for (int ct = 0; ct < 8; ++ct) {
        attsf[ct] = att_s[ct * 16 + lm];
        attdf[ct] = att_d[ct * 16 + lm];
    }
#pragma unroll
    for (int reg = 0; reg < 4; ++reg) {
        int row = m0 + rw0 + quad * 4 + reg;
        float ps = 0.f, pd = 0.f;
#pragma unroll
        for (int ct = 0; ct < 8; ++ct) {
            float v = acc[ct][reg];
            ps = fmaf(v, attsf[ct], ps);
            pd = fmaf(v, attdf[ct], pd);
        }
#pragma unroll
        for (int o = 8; o; o >>= 1) {
            ps += __shfl_xor(ps, o);
            pd += __shfl_xor(pd, o);
        }
        if (row < N_NODES) {
            if (lm == 0) { o_as[row] = ps; o_ad[row] = pd; }
#pragma unroll
            for (int ct = 0; ct < 8; ++ct)
                h2[(size_t)row * HID + ct * 16 + lm] = (__bf16)acc[ct][reg];
        }
    }
}

// ---------------------------------------------------------------- CSR build
// hist also records each edge's slot within its dst row (epos) -- scatter then
// needs NO atomic (the only atomic pass over edges is this one).
__global__ void hist_kernel(const int* __restrict__ ei, int* __restrict__ deg,
                            int* __restrict__ epos) {
    int e = blockIdx.x * 256 + threadIdx.x;
    if (e < N_EDGES) epos[e] = atomicAdd(&deg[ei[N_EDGES + e]], 1);
}

__global__ void scan1_kernel(const int* __restrict__ deg, int* __restrict__ bsum) {
    int b = blockIdx.x, t = threadIdx.x;
    int base = b * 1024 + t * 4;
    int s = 0;
#pragma unroll
    for (int j = 0; j < 4; ++j) {
        int idx = base + j;
        if (idx < N_NODES) s += deg[idx];
    }
    for (int o = 32; o; o >>= 1) s += __shfl_xor(s, o);
    __shared__ int wsum[4];
    int lane = t & 63, w = t >> 6;
    if (lane == 0) wsum[w] = s;
    __syncthreads();
    if (t == 0) bsum[b] = wsum[0] + wsum[1] + wsum[2] + wsum[3];
}

__global__ void scan2_kernel(const int* __restrict__ bsum, int* __restrict__ boff,
                             int* __restrict__ rowstart, int nb) {
    if (threadIdx.x == 0 && blockIdx.x == 0) {
        int run = 0;
        for (int i = 0; i < nb; ++i) { boff[i] = run; run += bsum[i]; }
        rowstart[N_NODES] = run;
    }
}

__global__ void scan3_kernel(const int* __restrict__ deg, const int* __restrict__ boff,
                             int* __restrict__ rowstart) {
    int b = blockIdx.x, t = threadIdx.x;
    int base = b * 1024 + t * 4;
    int v[4]; int s = 0;
#pragma unroll
    for (int j = 0; j < 4; ++j) {
        int idx = base + j;
        v[j] = (idx < N_NODES) ? deg[idx] : 0;
        s += v[j];
    }
    int lane = t & 63, w = t >> 6;
    int inc = s;
    for (int o = 1; o < 64; o <<= 1) {
        int u = __shfl_up(inc, o);
        if (lane >= o) inc += u;
    }
    __shared__ int wt[4];
    if (lane == 63) wt[w] = inc;
    __syncthreads();
    int woff = 0;
    for (int i = 0; i < w; ++i) woff += wt[i];
    int run = woff + inc - s + boff[b];
#pragma unroll
    for (int j = 0; j < 4; ++j) {
        int idx = base + j;
        if (idx < N_NODES) {
            rowstart[idx] = run;
            run += v[j];
        }
    }
}

// scatter (atomic-free): slot = rowstart[d] + epos[e]; payload (src, a_src[src]).
__global__ void scatter_kernel(const int* __restrict__ ei, const int* __restrict__ rowstart,
                               const int* __restrict__ epos, uint2* __restrict__ csrp,
                               const float* __restrict__ a_src) {
    int e = blockIdx.x * 256 + threadIdx.x;
    if (e >= N_EDGES) return;
    int s = ei[e], d = ei[N_EDGES + e];
    uint2 v; v.x = (unsigned)s; v.y = __float_as_uint(a_src[s]);
    csrp[rowstart[d] + epos[e]] = v;
}

// ---------------------------------------------------------------- aggregate+pool
// PERSISTENT WAVES: 6144 waves (24/CU at launch_bounds(256,6), VGPR cap 85 -> no
// spill). Lane owns features {2n,2n+1}; 16-deep register batch of shfl-broadcast
// (src,p) -> 16 independent row-gathers in flight. Invalid lanes carry (0,0) so
// the last batch runs full-width with zero-weight row-0 gathers (L1-hit, free).
// Graph-max pooled in registers, flushed on graph change.
__global__ __launch_bounds__(256, 6) void aggregate_kernel(
    const unsigned* __restrict__ h2u, const float* __restrict__ a_src,
    const float* __restrict__ a_dst, const int* __restrict__ rowstart,
    const uint2* __restrict__ csrp, const float* __restrict__ bias,
    const int* __restrict__ batch, float* __restrict__ out) {
    const int wid = threadIdx.x >> 6, lane = threadIdx.x & 63;
    const int w = blockIdx.x * 4 + wid;
    const int q = N_NODES / AGG_WAVES;
    const int r = N_NODES - q * AGG_WAVES;
    int n0 = w * q + (w < r ? w : r);
    int n1 = n0 + q + (w < r ? 1 : 0);
    const float b0 = bias[2 * lane], b1 = bias[2 * lane + 1];

    int gcur = -1;
    float m0 = 0.f, m1 = 0.f;
    for (int n = n0; n < n1; ++n) {
        int rs = rowstart[n], re = rowstart[n + 1];
        float adn = a_dst[n];
        float pself = __expf(lrelu(a_src[n] + adn));
        float2 hv = bf2f(h2u[(size_t)n * 64 + lane]);
        float denom = pself;
        float2 acc = make_float2(pself * hv.x, pself * hv.y);
        for (int base = rs; base < re; base += 64) {
            int cnt = re - base; if (cnt > 64) cnt = 64;
            uint2 sp = make_uint2(0u, 0u);
            bool valid = (base + lane < re);
            if (valid) sp = csrp[base + lane];
            float pe = valid ? __expf(lrelu(__uint_as_float(sp.y) + adn)) : 0.f;
            float ds = pe;
            for (int o = 32; o; o >>= 1) ds += __shfl_xor(ds, o);
            denom += ds;
            for (int e = 0; e < cnt; e += 16) {
                unsigned uu[16]; float pp[16];
#pragma unroll
                for (int i = 0; i < 16; ++i) {
                    unsigned src = (unsigned)__shfl((int)sp.x, e + i);
                    pp[i] = __shfl(pe, e + i);
                    uu[i] = h2u[(size_t)src * 64 + lane];
                }
#pragma unroll
                for (int i = 0; i < 16; ++i) {
                    float2 g = bf2f(uu[i]);
                    acc.x = fmaf(pp[i], g.x, acc.x);
                    acc.y = fmaf(pp[i], g.y, acc.y);
                }
            }
        }
        float inv = 1.0f / denom;
        float o0 = fmaxf(acc.x * inv + b0, 0.0f);
        float o1 = fmaxf(acc.y * inv + b1, 0.0f);
        int g = batch[n];
        if (g != gcur) {
            if (gcur >= 0) {
                unsigned* outp = (unsigned*)(out + (size_t)gcur * HID);
                atomicMax(&outp[2 * lane], __float_as_uint(m0));
                atomicMax(&outp[2 * lane + 1], __float_as_uint(m1));
            }
            gcur = g; m0 = o0; m1 = o1;
        } else {
            m0 = fmaxf(m0, o0); m1 = fmaxf(m1, o1);
        }
    }
    if (gcur >= 0) {
        unsigned* outp = (unsigned*)(out + (size_t)gcur * HID);
        atomicMax(&outp[2 * lane], __float_as_uint(m0));
        atomicMax(&outp[2 * lane + 1], __float_as_uint(m1));
    }
}

// ---------------------------------------------------------------- launch
extern "C" void kernel_launch(void* const* d_in, const int* in_sizes, int n_in,
                              void* d_out, int out_size, void* d_ws, size_t ws_size,
                              hipStream_t stream) {
    const float* x     = (const float*)d_in[0];
    const float* W     = (const float*)d_in[1];
    const float* att_s = (const float*)d_in[2];
    const float* att_d = (const float*)d_in[3];
    const float* bias  = (const float*)d_in[4];
    const int*   ei    = (const int*)d_in[5];
    const int*   batch = (const int*)d_in[6];
    float*       out   = (float*)d_out;

    char* ws = (char*)d_ws;
    size_t off = 0;
    auto alloc = [&](size_t bytes) -> void* {
        void* p = ws + off;
        off += (bytes + 255) & ~(size_t)255;
        return p;
    };
    const int NB = (N_NODES + 1023) / 1024;   // 49
    __bf16* h2       = (__bf16*)alloc((size_t)N_NODES * HID * 2);
    __bf16* wt       = (__bf16*)alloc((size_t)HID * IN_DIM * 2);
    float*  a_src    = (float*)alloc((size_t)N_NODES * 4);
    float*  a_dst    = (float*)alloc((size_t)N_NODES * 4);
    int*    deg      = (int*)alloc((size_t)N_NODES * 4);
    int*    rowstart = (int*)alloc((size_t)(N_NODES + 1) * 4);
    int*    bsum     = (int*)alloc((size_t)NB * 4);
    int*    boff     = (int*)alloc((size_t)NB * 4);
    int*    epos     = (int*)alloc((size_t)N_EDGES * 4);
    uint2*  csrp     = (uint2*)alloc((size_t)N_EDGES * 8);
    (void)ws_size; (void)in_sizes; (void)n_in;

    hipLaunchKernelGGL(prep_kernel, dim3(512), dim3(256), 0, stream,
                       W, wt, deg, out, out_size);
    hipLaunchKernelGGL(gemm_kernel, dim3((N_NODES + 63) / 64), dim3(256), 0, stream,
                       x, wt, h2, att_s, att_d, a_src, a_dst);
    hipLaunchKernelGGL(hist_kernel, dim3((N_EDGES + 255) / 256), dim3(256), 0, stream,
                       ei, deg, epos);
    hipLaunchKernelGGL(scan1_kernel, dim3(NB), dim3(256), 0, stream, deg, bsum);
    hipLaunchKernelGGL(scan2_kernel, dim3(1), dim3(64), 0, stream, bsum, boff, rowstart, NB);
    hipLaunchKernelGGL(scan3_kernel, dim3(NB), dim3(256), 0, stream, deg, boff, rowstart);
    hipLaunchKernelGGL(scatter_kernel, dim3((N_EDGES + 255) / 256), dim3(256), 0, stream,
                       ei, rowstart, epos, csrp, a_src);
    hipLaunchKernelGGL(aggregate_kernel, dim3(AGG_WAVES / 4), dim3(256), 0, stream,
                       (const unsigned*)h2, a_src, a_dst, rowstart, csrp, bias, batch, out);
}